// Round 4
// baseline (263.848 us; speedup 1.0000x reference)
//
#include <hip/hip_runtime.h>

// z_{t+1} = z_t @ K, T=256, B=256, D=512. out[b,t,d] = (z0 @ K^{t+1})[b,d], fp32.
//
// Multi-kernel ladder (cooperative fusion measured 2.3x WORSE — grid.sync at
// 512 blocks costs more than kernel boundaries on 8-XCD gfx950).
//
// Chunked matrix powers, c=16 (ladder depth 8 = log2(256), irreducible),
// bf16x3 split precision. U_j = z0 @ K^{16j} built by doubling batched into
// the squaring stages. Output phase out[16j+i-1] = U_j @ K^i (plain bf16).
//
// R3 change: output jobs PIGGYBACK on ladder stages as soon as their inputs
// (U_j, PT_i) exist: z=0 on s1, z=1 on s2, z=2..3 on s3, z=4..7 on s4,
// z=8..15 on s5, z=16..31 on s6, z=32..63 on s7, z=64..127 on s8. 1024 of
// 2048 out jobs run on idle CUs inside the latency/boundary shadow of the
// tiny ladder grids; the final gemm_out dispatch halves to 1024 WGs.
//
// ALL intermediates fragment-packed: 1KB chunks = exactly what 64 lanes of one
// 16x16x32 MFMA fragment read (elem = chunk*512 + lane*8 + j). A-operands load
// straight from global (coalesced dwordx4); B panels CONTIGUOUS in global ->
// staged as consecutive 1KB gll16's. Slot layout: [Apk-hi|Apk-lo|Bpk-hi|Bpk-lo].
// Dead forms elided via rowmask/tlomask.

typedef unsigned short u16;
typedef unsigned int u32;
typedef __bf16 bf16x8 __attribute__((ext_vector_type(8)));
typedef float f32x4 __attribute__((ext_vector_type(4)));
typedef u16 u16x4 __attribute__((ext_vector_type(4)));
typedef u16 u16x8 __attribute__((ext_vector_type(8)));

#define MAT 262144    /* 512*512 elems */
#define SLOT 1048576  /* 4*MAT u16 per power slot */
#define WSLOT 131072  /* 256*512 */

__device__ __forceinline__ u16 f2b(float f) {  // fp32 -> bf16 (RNE)
  u32 x = __float_as_uint(f);
  return (u16)((x + 0x7fffu + ((x >> 16) & 1u)) >> 16);
}
__device__ __forceinline__ float b2f(u16 u) { return __uint_as_float(((u32)u) << 16); }

// fragment-packed index for element (r, k), K-dim = 512
__device__ __forceinline__ size_t pidx(int r, int k) {
  return (size_t)(((r >> 4) * 16 + (k >> 5)) * 512 + ((k >> 3) & 3) * 128 + (r & 15) * 8 + (k & 7));
}

__device__ __forceinline__ void gll16(const void* g, void* l) {
  __builtin_amdgcn_global_load_lds((__attribute__((address_space(1))) void*)(void*)g,
                                   (__attribute__((address_space(3))) void*)l, 16, 0, 0);
}

// ---- prep: pack K into slot0 (4 forms); split z0 -> U_0 hi (Uh) + lo (Ul) ----
__global__ __launch_bounds__(256) void prep_kernel(const float* __restrict__ Kc,
                                                   const float* __restrict__ z0,
                                                   u16* __restrict__ P,
                                                   u16* __restrict__ Uh,
                                                   u16* __restrict__ Ul) {
  int tid = threadIdx.x, b = blockIdx.x;
  if (b < 64) {
    int r0 = (b >> 3) * 64, c0b = (b & 7) * 64;
#pragma unroll
    for (int q = 0; q < 2; ++q) {
      int g = q * 256 + tid;            // 512 groups: 64 rows x 8 col-groups
      int r = r0 + (g >> 3), c0 = c0b + (g & 7) * 8;
      float4 v0 = *(const float4*)(Kc + (size_t)r * 512 + c0);
      float4 v1 = *(const float4*)(Kc + (size_t)r * 512 + c0 + 4);
      float v[8] = {v0.x, v0.y, v0.z, v0.w, v1.x, v1.y, v1.z, v1.w};
      u16x8 h8, l8v;
#pragma unroll
      for (int j = 0; j < 8; ++j) {
        u16 h = f2b(v[j]);
        h8[j] = h;
        l8v[j] = f2b(v[j] - b2f(h));
        size_t ib = pidx(c0 + j, r);    // transposed form, scalar
        P[2 * MAT + ib] = h;
        P[3 * MAT + ib] = l8v[j];
      }
      size_t ia = pidx(r, c0);          // row form, contiguous 8 -> 16B stores
      *(u16x8*)(P + ia) = h8;
      *(u16x8*)(P + MAT + ia) = l8v;
    }
  } else {
    int idb = b - 64;  // 16 blocks x 4 iters x 256 threads x 8 elems = 131072
#pragma unroll
    for (int q = 0; q < 4; ++q) {
      int g = (idb * 4 + q) * 256 + tid;
      int r = g >> 6, c0 = (g & 63) * 8;
      float4 v0 = *(const float4*)(z0 + (size_t)r * 512 + c0);
      float4 v1 = *(const float4*)(z0 + (size_t)r * 512 + c0 + 4);
      float v[8] = {v0.x, v0.y, v0.z, v0.w, v1.x, v1.y, v1.z, v1.w};
      u16x8 h8, l8v;
#pragma unroll
      for (int j = 0; j < 8; ++j) {
        u16 h = f2b(v[j]);
        h8[j] = h;
        l8v[j] = f2b(v[j] - b2f(h));
      }
      size_t ia = pidx(r, c0);
      *(u16x8*)(Uh + ia) = h8;
      *(u16x8*)(Ul + ia) = l8v;
    }
  }
}

// ---- out job (64KB one-shot staging): out[:, zo, :] = U_{zo>>4} @ K^{(zo&15)+1}
__device__ __forceinline__ void out_job64(u16* Bs, int tid, int x, int zo,
                                          const u16* __restrict__ Ub,
                                          const u16* __restrict__ PT0,
                                          float* __restrict__ out) {
  const u16* A = Ub + (size_t)(zo >> 4) * WSLOT;
  const u16* Bt = PT0 + (size_t)(zo & 15) * SLOT;
  int n0 = x * 64;
  int wv = tid >> 6, lane = tid & 63;
  int mrow = lane & 15, quad = lane >> 4;
  int l8 = lane * 8;
  const u16* pb = Bt + (size_t)(n0 >> 4) * 16 * 512;  // contiguous 64KB panel
#pragma unroll
  for (int i = 0; i < 16; ++i) {
    int ch = wv * 16 + i;
    gll16(pb + (size_t)ch * 512 + l8, Bs + ch * 512);
  }
  __syncthreads();
  int mc0 = wv * 4;                      // wave-tile 64x64
  f32x4 acc[4][4] = {};
#pragma unroll 4
  for (int kt = 0; kt < 16; ++kt) {
    bf16x8 a[4], b[4];
#pragma unroll
    for (int mt = 0; mt < 4; ++mt)
      a[mt] = *(const bf16x8*)(A + (size_t)((mc0 + mt) * 16 + kt) * 512 + l8);
#pragma unroll
    for (int nt = 0; nt < 4; ++nt)
      b[nt] = *(const bf16x8*)(Bs + (nt * 16 + kt) * 512 + l8);
#pragma unroll
    for (int mt = 0; mt < 4; ++mt)
#pragma unroll
      for (int nt = 0; nt < 4; ++nt)
        acc[mt][nt] = __builtin_amdgcn_mfma_f32_16x16x32_bf16(a[mt], b[nt], acc[mt][nt], 0, 0, 0);
  }
#pragma unroll
  for (int mt = 0; mt < 4; ++mt)
#pragma unroll
    for (int nt = 0; nt < 4; ++nt) {
      int gb = wv * 64 + mt * 16 + quad * 4;
      int gd = n0 + nt * 16 + mrow;
#pragma unroll
      for (int r = 0; r < 4; ++r)
        out[((size_t)(gb + r) * 256 + zo) * 512 + gd] = acc[mt][nt][r];
    }
}

// ---- merged ladder stage + piggybacked out jobs.
// y < 8*nfull         : full DxD job, C 4-form slot (gated by rowmask/tlomask).
// 8*nfull <= y < ny0  : U job u=(y-8*nfull)>>2, 256-row quarter GEMM.
// y >= ny0            : out job e = ((y-ny0)*gridDim.z + z)*16 + x;
//                       xo = e&7, zo = zbase + (e>>3); idle if e >= nout.
__global__ __launch_bounds__(256, 2) void gemm_stage(
    const u16* __restrict__ fA, long fAstr,
    u16* __restrict__ fC, long fCstr,
    const u16* __restrict__ Bh, int nfull, int rowmask, int tlomask,
    const u16* __restrict__ UA, u16* __restrict__ UC,
    const u16* __restrict__ PT0, float* __restrict__ out,
    int ny0, int nout, int zbase) {
  __shared__ u16 Bs[32768];  // 64KB
  int tid = threadIdx.x;
  int z = blockIdx.z, y = blockIdx.y;
  if (y >= ny0) {            // piggybacked output job
    int e = ((y - ny0) * (int)gridDim.z + z) * 16 + (int)blockIdx.x;
    if (e < nout) out_job64(Bs, tid, e & 7, zbase + (e >> 3), UA, PT0, out);
    return;
  }
  const u16 *Ah, *Al;
  u16 *Ch, *Clo, *CTh, *CTl;
  int m0;
  bool full = (y < 8 * nfull);
  bool wrow, wtlo;
  if (full) {
    Ah = fA + (size_t)z * fAstr;
    Al = Ah + MAT;
    Ch = fC + (size_t)z * fCstr;
    Clo = Ch + MAT;
    CTh = Ch + 2 * MAT;
    CTl = Ch + 3 * MAT;
    m0 = y * 64;
    wrow = (rowmask >> z) & 1;
    wtlo = (tlomask >> z) & 1;
  } else {
    int yy = y - 8 * nfull;
    int u = yy >> 2;
    Ah = UA + (size_t)u * WSLOT;
    Al = Ah + 16 * (size_t)WSLOT;
    Ch = UC + (size_t)u * WSLOT;
    Clo = Ch + 16 * (size_t)WSLOT;
    CTh = CTl = nullptr;
    m0 = (yy & 3) * 64;
    wrow = true;
    wtlo = false;
  }
  const u16* Bl = Bh + MAT;
  int n0 = blockIdx.x * 32;
  int wv = tid >> 6, lane = tid & 63;
  int mrow = lane & 15, quad = lane >> 4;
  int l8 = lane * 8;
  int nchunk0 = n0 >> 4;                 // 2 nchunks x 16 kchunks = 32 chunks/form
  const u16* ph = Bh + (size_t)nchunk0 * 16 * 512;  // contiguous 32KB panel
  const u16* pl = Bl + (size_t)nchunk0 * 16 * 512;
#pragma unroll
  for (int i = 0; i < 8; ++i) {          // wave wv stages chunks wv*8+i (hi & lo)
    int ch = wv * 8 + i;
    gll16(ph + (size_t)ch * 512 + l8, Bs + ch * 512);
    gll16(pl + (size_t)ch * 512 + l8, Bs + 16384 + ch * 512);
  }
  __syncthreads();                       // the ONLY barrier
  int mc = (m0 >> 4) + wv;               // wave-tile 16x32 (4-way m-split)
  f32x4 acc[2] = {};
#pragma unroll 4
  for (int kt = 0; kt < 16; ++kt) {
    size_t co = (size_t)(mc * 16 + kt) * 512 + l8;
    bf16x8 ah = *(const bf16x8*)(Ah + co);
    bf16x8 al = *(const bf16x8*)(Al + co);
#pragma unroll
    for (int nt = 0; nt < 2; ++nt) {
      bf16x8 bh = *(const bf16x8*)(Bs + (nt * 16 + kt) * 512 + l8);
      bf16x8 bl = *(const bf16x8*)(Bs + 16384 + (nt * 16 + kt) * 512 + l8);
      acc[nt] = __builtin_amdgcn_mfma_f32_16x16x32_bf16(ah, bh, acc[nt], 0, 0, 0);
      acc[nt] = __builtin_amdgcn_mfma_f32_16x16x32_bf16(al, bh, acc[nt], 0, 0, 0);
      acc[nt] = __builtin_amdgcn_mfma_f32_16x16x32_bf16(ah, bl, acc[nt], 0, 0, 0);
    }
  }
  // C/D layout: col = lane&15, row = quad*4 + reg
  int mbase = m0 + wv * 16 + quad * 4;
#pragma unroll
  for (int nt = 0; nt < 2; ++nt) {
    int n = n0 + nt * 16 + mrow;
    u16x4 h4, l4;
#pragma unroll
    for (int r = 0; r < 4; ++r) {
      float v = acc[nt][r];
      u16 h = f2b(v);
      h4[r] = h;
      l4[r] = f2b(v - b2f(h));
    }
    if (wrow) {
#pragma unroll
      for (int r = 0; r < 4; ++r) {
        size_t ia = pidx(mbase + r, n);
        Ch[ia] = h4[r];
        Clo[ia] = l4[r];
      }
    }
    if (full) {
      size_t ib = pidx(n, mbase);        // 4 consecutive u16 (m&7 = quad&1*4 + r)
      *(u16x4*)(CTh + ib) = h4;
      if (wtlo) *(u16x4*)(CTl + ib) = l4;
    }
  }
}

// ---- final out phase: z = blockIdx.z + zofs. B panel staged in TWO 32KB
// halves through one 32KB buffer -> 4 blocks/CU (16 waves/CU). 3 barriers.
__global__ __launch_bounds__(256, 4) void gemm_out(const u16* __restrict__ Wb,
                                                   const u16* __restrict__ PT0,
                                                   float* __restrict__ out, int zofs) {
  __shared__ u16 Bs[16384];  // 32KB: 4 nchunks x 8 kchunks
  int z = blockIdx.z + zofs;
  const u16* A = Wb + (size_t)(z >> 4) * WSLOT;
  const u16* Bt = PT0 + (size_t)(z & 15) * SLOT;
  int tid = threadIdx.x;
  int n0 = blockIdx.x * 64;
  int wv = tid >> 6, lane = tid & 63;
  int mrow = lane & 15, quad = lane >> 4;
  int l8 = lane * 8;
  const u16* pb = Bt + (size_t)(n0 >> 4) * 16 * 512;  // contiguous 64KB panel
  int mc0 = wv * 4;                      // wave-tile 64x64
  f32x4 acc[4][4] = {};
#pragma unroll
  for (int h = 0; h < 2; ++h) {
    // stage half h: kchunks 8h..8h+7 of each of 4 nchunks -> 32 chunks of 1KB
#pragma unroll
    for (int i = 0; i < 8; ++i) {
      int c = wv * 8 + i;                // c = nc*8 + kc
      int nc = c >> 3, kc = c & 7;
      gll16(pb + (size_t)(nc * 16 + h * 8 + kc) * 512 + l8, Bs + c * 512);
    }
    __syncthreads();                     // staging done (drains vmcnt)
#pragma unroll 4
    for (int kt = 0; kt < 8; ++kt) {
      int ktg = h * 8 + kt;
      bf16x8 a[4], b[4];
#pragma unroll
      for (int mt = 0; mt < 4; ++mt)
        a[mt] = *(const bf16x8*)(A + (size_t)((mc0 + mt) * 16 + ktg) * 512 + l8);
#pragma unroll
      for (int nt = 0; nt < 4; ++nt)
        b[nt] = *(const bf16x8*)(Bs + (nt * 8 + kt) * 512 + l8);
#pragma unroll
      for (int mt = 0; mt < 4; ++mt)
#pragma unroll
        for (int nt = 0; nt < 4; ++nt)
          acc[mt][nt] = __builtin_amdgcn_mfma_f32_16x16x32_bf16(a[mt], b[nt], acc[mt][nt], 0, 0, 0);
    }
    if (h == 0) __syncthreads();         // all waves done reading before restage
  }
#pragma unroll
  for (int mt = 0; mt < 4; ++mt)
#pragma unroll
    for (int nt = 0; nt < 4; ++nt) {
      int gb = wv * 64 + mt * 16 + quad * 4;
      int gd = n0 + nt * 16 + mrow;
#pragma unroll
      for (int r = 0; r < 4; ++r)
        out[((size_t)(gb + r) * 256 + z) * 512 + gd] = acc[mt][nt][r];
    }
}

extern "C" void kernel_launch(void* const* d_in, const int* in_sizes, int n_in,
                              void* d_out, int out_size, void* d_ws, size_t ws_size,
                              hipStream_t stream) {
  const float* z0 = (const float*)d_in[0];
  const float* Kc = (const float*)d_in[1];
  float* out = (float*)d_out;
  // ws layout (u16): Uh[16*WSLOT] | Ul[16*WSLOT] | P[19*SLOT]
  // P slots: 0..15 = K^1..K^16; 16 = K^32; 17 = K^64; 18 = K^128
  u16* Uh = (u16*)d_ws;
  u16* Ul = Uh + 16 * (size_t)WSLOT;
  u16* P = Ul + 16 * (size_t)WSLOT;
  u16* PT = P + 2 * MAT;  // T-hi form of slot 0, stride SLOT
  auto S = [&](int s) { return P + (size_t)s * SLOT; };
  dim3 blk(256);

  prep_kernel<<<80, blk, 0, stream>>>(Kc, z0, P, Uh, Ul);
  // small powers + piggybacked out jobs (z rides as soon as U_j & PT_i exist)
  // s1: K^2                       + out z=0      (8 jobs)
  gemm_stage<<<dim3(16, 9, 1), blk, 0, stream>>>(S(0), 0, S(1), 0, S(0) + 2 * MAT, 1, 0x1, 0x1, Uh, nullptr, PT, out, 8, 8, 0);
  // s2: K^3,K^4                   + out z=1      (8)
  gemm_stage<<<dim3(16, 9, 2), blk, 0, stream>>>(S(0), SLOT, S(2), SLOT, S(1) + 2 * MAT, 1, 0x3, 0x2, Uh, nullptr, PT, out, 8, 8, 1);
  // s3: K^5..8                    + out z=2,3    (16)
  gemm_stage<<<dim3(16, 9, 4), blk, 0, stream>>>(S(0), SLOT, S(4), SLOT, S(3) + 2 * MAT, 1, 0xF, 0x8, Uh, nullptr, PT, out, 8, 16, 2);
  // s4: K^9..16                   + out z=4..7   (32)
  gemm_stage<<<dim3(16, 9, 8), blk, 0, stream>>>(S(0), SLOT, S(8), SLOT, S(7) + 2 * MAT, 1, 0x80, 0x80, Uh, nullptr, PT, out, 8, 32, 4);
  // s5: K^32 + U_1                + out z=8..15  (64)
  gemm_stage<<<dim3(16, 16, 1), blk, 0, stream>>>(S(15), 0, S(16), 0, S(15) + 2 * MAT, 1, 0x1, 0x1, Uh, Uh + 1 * (size_t)WSLOT, PT, out, 12, 64, 8);
  // s6: K^64 + U_{2,3}            + out z=16..31 (128)
  gemm_stage<<<dim3(16, 24, 1), blk, 0, stream>>>(S(16), 0, S(17), 0, S(16) + 2 * MAT, 1, 0x1, 0x1, Uh, Uh + 2 * (size_t)WSLOT, PT, out, 16, 128, 16);
  // s7: K^128 + U_{4..7}          + out z=32..63 (256)   (K^128 row forms unused)
  gemm_stage<<<dim3(16, 40, 1), blk, 0, stream>>>(S(17), 0, S(18), 0, S(17) + 2 * MAT, 1, 0x0, 0x1, Uh, Uh + 4 * (size_t)WSLOT, PT, out, 24, 256, 32);
  // s8: U_{8..15}                 + out z=64..127 (512)
  gemm_stage<<<dim3(16, 64, 1), blk, 0, stream>>>(S(18), 0, S(18), 0, S(18) + 2 * MAT, 0, 0x0, 0x0, Uh, Uh + 8 * (size_t)WSLOT, PT, out, 32, 512, 64);
  // final out phase: z=128..255, 1024 WGs
  gemm_out<<<dim3(8, 1, 128), blk, 0, stream>>>(Uh, PT, out, 128);
}

// Round 5
// 241.980 us; speedup vs baseline: 1.0904x; 1.0904x over previous
//
#include <hip/hip_runtime.h>

// z_{t+1} = z_t @ K, T=256, B=256, D=512. out[b,t,d] = (z0 @ K^{t+1})[b,d], fp32.
//
// Multi-kernel ladder (R2 structure @ 240.6us; cooperative fusion was 2.3x
// WORSE; R3 piggybacking out-jobs onto ladder stages was +23us WORSE because
// out jobs are longer than ladder jobs and extend each stage's critical path).
//
// Chunked matrix powers, c=16 (ladder depth 8 = log2(256), irreducible),
// bf16x3 split precision. U_j = z0 @ K^{16j} built by doubling batched into
// the squaring stages. Output phase out[16j+i-1] = U_j @ K^i (plain bf16).
//
// R4 change: gemm_out grid is Z-MAJOR (grid (256,1,8): blockIdx.x = z,
// blockIdx.z = x-tile). Linear block id = z + 256*x -> XCD = z%8, so all 8
// x-tiles of one z land on the SAME XCD: U_j and PT_i panels become
// L2-resident per XCD instead of being re-fetched from L3 by 8 XCDs
// (was grid (8,1,256): XCD = x%8, maximal spread).
//
// ALL intermediates fragment-packed: 1KB chunks = exactly what 64 lanes of one
// 16x16x32 MFMA fragment read (elem = chunk*512 + lane*8 + j). A-operands load
// straight from global (coalesced dwordx4); B panels CONTIGUOUS in global ->
// staged as consecutive 1KB gll16's. Slot layout: [Apk-hi|Apk-lo|Bpk-hi|Bpk-lo].
// Dead forms elided via rowmask/tlomask.

typedef unsigned short u16;
typedef unsigned int u32;
typedef __bf16 bf16x8 __attribute__((ext_vector_type(8)));
typedef float f32x4 __attribute__((ext_vector_type(4)));
typedef u16 u16x4 __attribute__((ext_vector_type(4)));
typedef u16 u16x8 __attribute__((ext_vector_type(8)));

#define MAT 262144    /* 512*512 elems */
#define SLOT 1048576  /* 4*MAT u16 per power slot */
#define WSLOT 131072  /* 256*512 */

__device__ __forceinline__ u16 f2b(float f) {  // fp32 -> bf16 (RNE)
  u32 x = __float_as_uint(f);
  return (u16)((x + 0x7fffu + ((x >> 16) & 1u)) >> 16);
}
__device__ __forceinline__ float b2f(u16 u) { return __uint_as_float(((u32)u) << 16); }

// fragment-packed index for element (r, k), K-dim = 512
__device__ __forceinline__ size_t pidx(int r, int k) {
  return (size_t)(((r >> 4) * 16 + (k >> 5)) * 512 + ((k >> 3) & 3) * 128 + (r & 15) * 8 + (k & 7));
}

__device__ __forceinline__ void gll16(const void* g, void* l) {
  __builtin_amdgcn_global_load_lds((__attribute__((address_space(1))) void*)(void*)g,
                                   (__attribute__((address_space(3))) void*)l, 16, 0, 0);
}

// ---- prep: pack K into slot0 (4 forms); split z0 -> U_0 hi (Uh) + lo (Ul) ----
__global__ __launch_bounds__(256) void prep_kernel(const float* __restrict__ Kc,
                                                   const float* __restrict__ z0,
                                                   u16* __restrict__ P,
                                                   u16* __restrict__ Uh,
                                                   u16* __restrict__ Ul) {
  int tid = threadIdx.x, b = blockIdx.x;
  if (b < 64) {
    int r0 = (b >> 3) * 64, c0b = (b & 7) * 64;
#pragma unroll
    for (int q = 0; q < 2; ++q) {
      int g = q * 256 + tid;            // 512 groups: 64 rows x 8 col-groups
      int r = r0 + (g >> 3), c0 = c0b + (g & 7) * 8;
      float4 v0 = *(const float4*)(Kc + (size_t)r * 512 + c0);
      float4 v1 = *(const float4*)(Kc + (size_t)r * 512 + c0 + 4);
      float v[8] = {v0.x, v0.y, v0.z, v0.w, v1.x, v1.y, v1.z, v1.w};
      u16x8 h8, l8v;
#pragma unroll
      for (int j = 0; j < 8; ++j) {
        u16 h = f2b(v[j]);
        h8[j] = h;
        l8v[j] = f2b(v[j] - b2f(h));
        size_t ib = pidx(c0 + j, r);    // transposed form, scalar
        P[2 * MAT + ib] = h;
        P[3 * MAT + ib] = l8v[j];
      }
      size_t ia = pidx(r, c0);          // row form, contiguous 8 -> 16B stores
      *(u16x8*)(P + ia) = h8;
      *(u16x8*)(P + MAT + ia) = l8v;
    }
  } else {
    int idb = b - 64;  // 16 blocks x 4 iters x 256 threads x 8 elems = 131072
#pragma unroll
    for (int q = 0; q < 4; ++q) {
      int g = (idb * 4 + q) * 256 + tid;
      int r = g >> 6, c0 = (g & 63) * 8;
      float4 v0 = *(const float4*)(z0 + (size_t)r * 512 + c0);
      float4 v1 = *(const float4*)(z0 + (size_t)r * 512 + c0 + 4);
      float v[8] = {v0.x, v0.y, v0.z, v0.w, v1.x, v1.y, v1.z, v1.w};
      u16x8 h8, l8v;
#pragma unroll
      for (int j = 0; j < 8; ++j) {
        u16 h = f2b(v[j]);
        h8[j] = h;
        l8v[j] = f2b(v[j] - b2f(h));
      }
      size_t ia = pidx(r, c0);
      *(u16x8*)(Uh + ia) = h8;
      *(u16x8*)(Ul + ia) = l8v;
    }
  }
}

// ---- merged ladder stage: one shared B panel (hi+lo, 64KB LDS, ONE barrier).
// blockIdx.y < 8*nfull  : full DxD job, C 4-form slot (writes gated by
//                         rowmask/tlomask bit z; T-hi always written).
// blockIdx.y >= 8*nfull : U job u = (y-8*nfull)>>2, 256-row quarter GEMM,
//                         row hi/lo forms only.
// All jobs bf16x3 split: acc += ah*bh + al*bh + ah*bl.
__global__ __launch_bounds__(256, 2) void gemm_stage(
    const u16* __restrict__ fA, long fAstr,
    u16* __restrict__ fC, long fCstr,
    const u16* __restrict__ Bh, int nfull, int rowmask, int tlomask,
    const u16* __restrict__ UA, u16* __restrict__ UC) {
  __shared__ u16 Bs[32768];  // [hi 32 chunks | lo 32 chunks] = 64KB
  int z = blockIdx.z, y = blockIdx.y;
  const u16 *Ah, *Al;
  u16 *Ch, *Clo, *CTh, *CTl;
  int m0;
  bool full = (y < 8 * nfull);
  bool wrow, wtlo;
  if (full) {
    Ah = fA + (size_t)z * fAstr;
    Al = Ah + MAT;
    Ch = fC + (size_t)z * fCstr;
    Clo = Ch + MAT;
    CTh = Ch + 2 * MAT;
    CTl = Ch + 3 * MAT;
    m0 = y * 64;
    wrow = (rowmask >> z) & 1;
    wtlo = (tlomask >> z) & 1;
  } else {
    int yy = y - 8 * nfull;
    int u = yy >> 2;
    Ah = UA + (size_t)u * WSLOT;
    Al = Ah + 16 * (size_t)WSLOT;
    Ch = UC + (size_t)u * WSLOT;
    Clo = Ch + 16 * (size_t)WSLOT;
    CTh = CTl = nullptr;
    m0 = (yy & 3) * 64;
    wrow = true;
    wtlo = false;
  }
  const u16* Bl = Bh + MAT;
  int tid = threadIdx.x;
  int n0 = blockIdx.x * 32;
  int wv = tid >> 6, lane = tid & 63;
  int mrow = lane & 15, quad = lane >> 4;
  int l8 = lane * 8;
  int nchunk0 = n0 >> 4;                 // 2 nchunks x 16 kchunks = 32 chunks/form
  const u16* ph = Bh + (size_t)nchunk0 * 16 * 512;  // contiguous 32KB panel
  const u16* pl = Bl + (size_t)nchunk0 * 16 * 512;
#pragma unroll
  for (int i = 0; i < 8; ++i) {          // wave wv stages chunks wv*8+i (hi & lo)
    int ch = wv * 8 + i;
    gll16(ph + (size_t)ch * 512 + l8, Bs + ch * 512);
    gll16(pl + (size_t)ch * 512 + l8, Bs + 16384 + ch * 512);
  }
  __syncthreads();                       // the ONLY barrier
  int mc = (m0 >> 4) + wv;               // wave-tile 16x32 (4-way m-split)
  f32x4 acc[2] = {};
#pragma unroll 4
  for (int kt = 0; kt < 16; ++kt) {
    size_t co = (size_t)(mc * 16 + kt) * 512 + l8;
    bf16x8 ah = *(const bf16x8*)(Ah + co);
    bf16x8 al = *(const bf16x8*)(Al + co);
#pragma unroll
    for (int nt = 0; nt < 2; ++nt) {
      bf16x8 bh = *(const bf16x8*)(Bs + (nt * 16 + kt) * 512 + l8);
      bf16x8 bl = *(const bf16x8*)(Bs + 16384 + (nt * 16 + kt) * 512 + l8);
      acc[nt] = __builtin_amdgcn_mfma_f32_16x16x32_bf16(ah, bh, acc[nt], 0, 0, 0);
      acc[nt] = __builtin_amdgcn_mfma_f32_16x16x32_bf16(al, bh, acc[nt], 0, 0, 0);
      acc[nt] = __builtin_amdgcn_mfma_f32_16x16x32_bf16(ah, bl, acc[nt], 0, 0, 0);
    }
  }
  // C/D layout: col = lane&15, row = quad*4 + reg
  int mbase = m0 + wv * 16 + quad * 4;
#pragma unroll
  for (int nt = 0; nt < 2; ++nt) {
    int n = n0 + nt * 16 + mrow;
    u16x4 h4, l4;
#pragma unroll
    for (int r = 0; r < 4; ++r) {
      float v = acc[nt][r];
      u16 h = f2b(v);
      h4[r] = h;
      l4[r] = f2b(v - b2f(h));
    }
    if (wrow) {
#pragma unroll
      for (int r = 0; r < 4; ++r) {
        size_t ia = pidx(mbase + r, n);
        Ch[ia] = h4[r];
        Clo[ia] = l4[r];
      }
    }
    if (full) {
      size_t ib = pidx(n, mbase);        // 4 consecutive u16 (m&7 = quad&1*4 + r)
      *(u16x4*)(CTh + ib) = h4;
      if (wtlo) *(u16x4*)(CTl + ib) = l4;
    }
  }
}

// ---- parallel phase: out[:, z, :] = U_{z>>4} @ K^{(z&15)+1}, plain bf16.
// Z-MAJOR grid: blockIdx.x = z (0..255), blockIdx.z = x-tile (0..7) so
// XCD = linear%8 = z%8 -> all 8 x-tiles of one z share an XCD (L2-resident
// U_j / PT_i panels). B panel staged in TWO 32KB halves through one 32KB
// buffer -> 4 blocks/CU (16 waves/CU). 3 barriers. 4-way m-split.
__global__ __launch_bounds__(256, 4) void gemm_out(const u16* __restrict__ Wb,
                                                   const u16* __restrict__ PT0,
                                                   float* __restrict__ out) {
  __shared__ u16 Bs[16384];  // 32KB: 4 nchunks x 8 kchunks
  int z = blockIdx.x;
  const u16* A = Wb + (size_t)(z >> 4) * WSLOT;
  const u16* Bt = PT0 + (size_t)(z & 15) * SLOT;
  int tid = threadIdx.x;
  int n0 = blockIdx.z * 64;
  int wv = tid >> 6, lane = tid & 63;
  int mrow = lane & 15, quad = lane >> 4;
  int l8 = lane * 8;
  const u16* pb = Bt + (size_t)(n0 >> 4) * 16 * 512;  // contiguous 64KB panel
  int mc0 = wv * 4;                      // wave-tile 64x64
  f32x4 acc[4][4] = {};
#pragma unroll
  for (int h = 0; h < 2; ++h) {
    // stage half h: kchunks 8h..8h+7 of each of 4 nchunks -> 32 chunks of 1KB
#pragma unroll
    for (int i = 0; i < 8; ++i) {
      int c = wv * 8 + i;                // c = nc*8 + kc, nc = c>>3, kc = c&7
      int nc = c >> 3, kc = c & 7;
      gll16(pb + (size_t)(nc * 16 + h * 8 + kc) * 512 + l8, Bs + c * 512);
    }
    __syncthreads();                     // staging done (drains vmcnt)
#pragma unroll 4
    for (int kt = 0; kt < 8; ++kt) {
      int ktg = h * 8 + kt;
      bf16x8 a[4], b[4];
#pragma unroll
      for (int mt = 0; mt < 4; ++mt)
        a[mt] = *(const bf16x8*)(A + (size_t)((mc0 + mt) * 16 + ktg) * 512 + l8);
#pragma unroll
      for (int nt = 0; nt < 4; ++nt)
        b[nt] = *(const bf16x8*)(Bs + (nt * 8 + kt) * 512 + l8);
#pragma unroll
      for (int mt = 0; mt < 4; ++mt)
#pragma unroll
        for (int nt = 0; nt < 4; ++nt)
          acc[mt][nt] = __builtin_amdgcn_mfma_f32_16x16x32_bf16(a[mt], b[nt], acc[mt][nt], 0, 0, 0);
    }
    if (h == 0) __syncthreads();         // all waves done reading before restage
  }
#pragma unroll
  for (int mt = 0; mt < 4; ++mt)
#pragma unroll
    for (int nt = 0; nt < 4; ++nt) {
      int gb = wv * 64 + mt * 16 + quad * 4;
      int gd = n0 + nt * 16 + mrow;
#pragma unroll
      for (int r = 0; r < 4; ++r)
        out[((size_t)(gb + r) * 256 + z) * 512 + gd] = acc[mt][nt][r];
    }
}

extern "C" void kernel_launch(void* const* d_in, const int* in_sizes, int n_in,
                              void* d_out, int out_size, void* d_ws, size_t ws_size,
                              hipStream_t stream) {
  const float* z0 = (const float*)d_in[0];
  const float* Kc = (const float*)d_in[1];
  float* out = (float*)d_out;
  // ws layout (u16): Uh[16*WSLOT] | Ul[16*WSLOT] | P[19*SLOT]
  // P slots: 0..15 = K^1..K^16; 16 = K^32; 17 = K^64; 18 = K^128
  u16* Uh = (u16*)d_ws;
  u16* Ul = Uh + 16 * (size_t)WSLOT;
  u16* P = Ul + 16 * (size_t)WSLOT;
  auto S = [&](int s) { return P + (size_t)s * SLOT; };
  dim3 blk(256);

  prep_kernel<<<80, blk, 0, stream>>>(Kc, z0, P, Uh, Ul);
  // small powers: K^2; {K^3,K^4}; {K^5..8}; {K^9..16}
  gemm_stage<<<dim3(16, 8, 1), blk, 0, stream>>>(S(0), 0, S(1), 0, S(0) + 2 * MAT, 1, 0x1, 0x1, nullptr, nullptr);
  gemm_stage<<<dim3(16, 8, 2), blk, 0, stream>>>(S(0), SLOT, S(2), SLOT, S(1) + 2 * MAT, 1, 0x3, 0x2, nullptr, nullptr);
  gemm_stage<<<dim3(16, 8, 4), blk, 0, stream>>>(S(0), SLOT, S(4), SLOT, S(3) + 2 * MAT, 1, 0xF, 0x8, nullptr, nullptr);
  gemm_stage<<<dim3(16, 8, 8), blk, 0, stream>>>(S(0), SLOT, S(8), SLOT, S(7) + 2 * MAT, 1, 0x80, 0x80, nullptr, nullptr);
  // doubling stages: power squaring + U-doubling share one B panel per launch
  // s5: K^32 = K^16@K^16  +  U_1 = U_0@K^16
  gemm_stage<<<dim3(16, 12, 1), blk, 0, stream>>>(S(15), 0, S(16), 0, S(15) + 2 * MAT, 1, 0x1, 0x1, Uh, Uh + 1 * (size_t)WSLOT);
  // s6: K^64 = K^32@K^32  +  U_{2,3} = U_{0,1}@K^32
  gemm_stage<<<dim3(16, 16, 1), blk, 0, stream>>>(S(16), 0, S(17), 0, S(16) + 2 * MAT, 1, 0x1, 0x1, Uh, Uh + 2 * (size_t)WSLOT);
  // s7: K^128 = K^64@K^64  +  U_{4..7} = U_{0..3}@K^64   (K^128 row forms unused)
  gemm_stage<<<dim3(16, 24, 1), blk, 0, stream>>>(S(17), 0, S(18), 0, S(17) + 2 * MAT, 1, 0x0, 0x1, Uh, Uh + 4 * (size_t)WSLOT);
  // s8: U_{8..15} = U_{0..7}@K^128
  gemm_stage<<<dim3(16, 32, 1), blk, 0, stream>>>(S(18), 0, S(18), 0, S(18) + 2 * MAT, 0, 0x0, 0x0, Uh, Uh + 8 * (size_t)WSLOT);
  // parallel phase: 2048 WGs, z-major for XCD/L2 locality
  gemm_out<<<dim3(256, 1, 8), blk, 0, stream>>>(Uh, P + 2 * MAT, out);
}